// Round 6
// baseline (699.041 us; speedup 1.0000x reference)
//
#include <hip/hip_runtime.h>
#include <hip/hip_bf16.h>
#include <stdint.h>

#define NB 64
#define NV 2048
#define NL 512
#define DK 512
#define BT 128
#define BK 64

typedef __attribute__((ext_vector_type(8))) short bf16x8;
typedef __attribute__((ext_vector_type(4))) float f32x4;

// order-preserving float -> uint map (for atomicMin); all-ones = +infinity sentinel
__device__ __forceinline__ unsigned enc_f(float f) {
  unsigned u = __float_as_uint(f);
  return (u & 0x80000000u) ? ~u : (u | 0x80000000u);
}
__device__ __forceinline__ float dec_f(unsigned u) {
  unsigned b = (u & 0x80000000u) ? (u ^ 0x80000000u) : ~u;
  return __uint_as_float(b);
}

// fp32 -> bf16 (RNE); inputs finite, no NaN path
__device__ __forceinline__ unsigned short f2bf(float f) {
  unsigned u = __float_as_uint(f);
  u += 0x7FFFu + ((u >> 16) & 1u);
  return (unsigned short)(u >> 16);
}
__device__ __forceinline__ unsigned pack_bf2(float lo, float hi) {
  return (unsigned)f2bf(lo) | ((unsigned)f2bf(hi) << 16);
}

// async global->LDS, 16 B per lane; LDS dest = wave-uniform base + lane*16
__device__ __forceinline__ void gload_lds16(const void* g, void* l) {
  __builtin_amdgcn_global_load_lds(
      (const __attribute__((address_space(1))) unsigned*)g,
      (__attribute__((address_space(3))) unsigned*)l, 16, 0, 0);
}

// ---------------- Pass 1: fp32 -> bf16 + exact fp32 row norms + min-sentinel init -------
// one wave per row of 512 floats; lane handles 8 consecutive elems -> one 16B store.
__global__ __launch_bounds__(256) void convert_norm(
    const float* __restrict__ video, const float* __restrict__ lang,
    unsigned short* __restrict__ Vb, unsigned short* __restrict__ Lb,
    float* __restrict__ vnorm, float* __restrict__ lnorm,
    unsigned* __restrict__ rowmin, unsigned* __restrict__ colmin) {
  const int t = threadIdx.x;
  const int lane = t & 63;
  const int row = blockIdx.x * 4 + (t >> 6);
  const int rows_v = NB * NV;

  const float* src;
  unsigned short* dst;
  float* nrm;
  unsigned* sent;
  size_t r;
  if (row < rows_v) { src = video; dst = Vb; nrm = vnorm; sent = rowmin; r = (size_t)row; }
  else              { src = lang;  dst = Lb;  nrm = lnorm; sent = colmin; r = (size_t)(row - rows_v); }

  const float4* p = (const float4*)(src + r * DK);
  const float4 a = p[lane * 2];
  const float4 b = p[lane * 2 + 1];

  float n = a.x * a.x + a.y * a.y + a.z * a.z + a.w * a.w
          + b.x * b.x + b.y * b.y + b.z * b.z + b.w * b.w;
  #pragma unroll
  for (int m = 1; m < 64; m <<= 1) n += __shfl_xor(n, m, 64);

  uint4 pk;
  pk.x = pack_bf2(a.x, a.y); pk.y = pack_bf2(a.z, a.w);
  pk.z = pack_bf2(b.x, b.y); pk.w = pack_bf2(b.z, b.w);
  ((uint4*)(dst + r * DK))[lane] = pk;
  if (lane == 0) {
    nrm[r] = n;
    sent[r] = 0xFFFFFFFFu;   // +inf sentinel for atomicMin
  }
}

// ---------------- Pass 2: bf16 GEMM + chamfer mins ----------------
// Round-0 verified structure (gemm ~118 us): 4096 one-tile blocks, 128x128 tile,
// 4 waves (64x64 out each), BK=64, 2-barrier K-loop, global_load_lds w=16,
// XOR chunk-swizzled LDS (0 bank conflicts). Short-lived blocks + dynamic refill
// sweep the tile space => L2/L3 locality (persistent variant measured 286 MB
// FETCH / 197 us vs this structure's ~118 us — do not make blocks persistent).
// ONLY delta vs round-0: launch_bounds min-waves 4 -> 5. LDS 32 KiB/block =>
// exactly 5 blocks/CU (160 KiB pool); VGPR=64 measured => regs allow it. 5th
// co-resident block adds waves to hide the vmcnt(0)+barrier drain.
__global__ __launch_bounds__(256, 5) void chamfer_gemm(
    const unsigned short* __restrict__ Vb, const unsigned short* __restrict__ Lb,
    const float* __restrict__ vnorm, const float* __restrict__ lnorm,
    unsigned* __restrict__ rowmin, unsigned* __restrict__ colmin) {
  __shared__ unsigned short Asm[BT][BK];
  __shared__ unsigned short Bsm[BT][BK];

  const int bid0 = blockIdx.x;
  const int bid = (bid0 & 7) * 512 + (bid0 >> 3);   // XCD-contiguous logical id
  const int b  = bid >> 6;
  const int vt = (bid >> 2) & 15;
  const int lt = bid & 3;

  const unsigned short* Ag = Vb + ((size_t)b * NV + (size_t)vt * BT) * DK;
  const unsigned short* Bg = Lb + ((size_t)b * NL + (size_t)lt * BT) * DK;

  const int t = threadIdx.x;
  const int lane = t & 63;
  const int w = t >> 6;
  const int wrow = (w >> 1) * 64;
  const int wcol = (w & 1) * 64;

  // staging: each wave stages 32 rows of A and 32 rows of B (4 instrs each, 8 rows/instr)
  const int lr = lane >> 3;        // row within 8-row group
  const int lp = lane & 7;         // dest slot within row
  const int schunk = lp ^ lr;      // source chunk (XOR swizzle)

  f32x4 acc[4][4];
  #pragma unroll
  for (int i = 0; i < 4; i++)
    #pragma unroll
    for (int j = 0; j < 4; j++)
      acc[i][j] = (f32x4){0.f, 0.f, 0.f, 0.f};

  const int c16 = lane & 15;
  const int hi  = lane >> 4;       // 0..3
  const int sw  = c16 & 7;         // read-side swizzle key (row&7)

  for (int k0 = 0; k0 < DK; k0 += BK) {
    __syncthreads();               // all waves done reading previous tile
    #pragma unroll
    for (int s = 0; s < 4; s++) {
      const int row = w * 32 + s * 8 + lr;
      gload_lds16(Ag + (size_t)row * DK + k0 + schunk * 8, &Asm[w * 32 + s * 8][0]);
      gload_lds16(Bg + (size_t)row * DK + k0 + schunk * 8, &Bsm[w * 32 + s * 8][0]);
    }
    __syncthreads();               // vmcnt(0) drain -> tile visible
    #pragma unroll
    for (int ks = 0; ks < 2; ks++) {
      const int ck = ks * 4 + hi;  // logical 16B chunk index in row
      bf16x8 af[4], bfr[4];
      #pragma unroll
      for (int i = 0; i < 4; i++)
        af[i] = *(const bf16x8*)&Asm[wrow + i * 16 + c16][(ck ^ sw) * 8];
      #pragma unroll
      for (int j = 0; j < 4; j++)
        bfr[j] = *(const bf16x8*)&Bsm[wcol + j * 16 + c16][(ck ^ sw) * 8];
      #pragma unroll
      for (int i = 0; i < 4; i++)
        #pragma unroll
        for (int j = 0; j < 4; j++)
          acc[i][j] = __builtin_amdgcn_mfma_f32_16x16x32_bf16(af[i], bfr[j], acc[i][j], 0, 0, 0);
    }
  }

  // epilogue: P = rn + cn - 2*dot; C layout col=lane&15, row=(lane>>4)*4+reg
  const int g = hi;
  const int c = c16;
  const size_t rowbase = (size_t)b * NV + (size_t)vt * BT + wrow;
  const size_t colbase = (size_t)b * NL + (size_t)lt * BT + wcol;

  float cn[4];
  #pragma unroll
  for (int j = 0; j < 4; j++) cn[j] = lnorm[colbase + j * 16 + c];

  float cmin[4];
  #pragma unroll
  for (int j = 0; j < 4; j++) cmin[j] = 3.0e38f;

  #pragma unroll
  for (int i = 0; i < 4; i++) {
    #pragma unroll
    for (int r = 0; r < 4; r++) {
      const float rn = vnorm[rowbase + i * 16 + g * 4 + r];
      float m = 3.0e38f;
      #pragma unroll
      for (int j = 0; j < 4; j++) {
        const float P = rn + cn[j] - 2.0f * acc[i][j][r];
        m = fminf(m, P);
        cmin[j] = fminf(cmin[j], P);
      }
      #pragma unroll
      for (int mm = 1; mm < 16; mm <<= 1)
        m = fminf(m, __shfl_xor(m, mm, 64));
      if (c == 0)
        atomicMin(&rowmin[rowbase + i * 16 + g * 4 + r], enc_f(m));
    }
  }
  #pragma unroll
  for (int j = 0; j < 4; j++) {
    float m = cmin[j];
    m = fminf(m, __shfl_xor(m, 16, 64));
    m = fminf(m, __shfl_xor(m, 32, 64));
    if (g == 0)
      atomicMin(&colmin[colbase + j * 16 + c], enc_f(m));
  }
}

__global__ void chamfer_reduce(const unsigned* __restrict__ rowmin,
                               const unsigned* __restrict__ colmin,
                               float* __restrict__ out) {
  const int b = blockIdx.x;
  const int t = threadIdx.x;
  float s = 0.f;
  for (int i = t; i < NV; i += 256) s += dec_f(rowmin[(size_t)b * NV + i]) * (1.0f / NV);
  for (int i = t; i < NL; i += 256) s += dec_f(colmin[(size_t)b * NL + i]) * (1.0f / NL);
  #pragma unroll
  for (int m = 1; m < 64; m <<= 1) s += __shfl_xor(s, m, 64);
  __shared__ float ws[4];
  if ((t & 63) == 0) ws[t >> 6] = s;
  __syncthreads();
  if (t == 0) out[b] = ws[0] + ws[1] + ws[2] + ws[3];
}

extern "C" void kernel_launch(void* const* d_in, const int* in_sizes, int n_in,
                              void* d_out, int out_size, void* d_ws, size_t ws_size,
                              hipStream_t stream) {
  const float* video = (const float*)d_in[0];
  const float* lang  = (const float*)d_in[1];
  float* out = (float*)d_out;

  const size_t vb_elems = (size_t)NB * NV * DK;   // 67.1M bf16
  const size_t lb_elems = (size_t)NB * NL * DK;   // 16.8M bf16

  unsigned short* Vb = (unsigned short*)d_ws;
  unsigned short* Lb = Vb + vb_elems;
  float* vnorm = (float*)(Lb + lb_elems);
  float* lnorm = vnorm + (size_t)NB * NV;         // vnorm holds NB*NV floats
  unsigned* rowmin = (unsigned*)(lnorm + (size_t)NB * NL);
  unsigned* colmin = rowmin + (size_t)NB * NV;

  convert_norm<<<dim3((NB * NV + NB * NL) / 4), dim3(256), 0, stream>>>(
      video, lang, Vb, Lb, vnorm, lnorm, rowmin, colmin);
  chamfer_gemm<<<dim3(NB * 16 * 4), dim3(256), 0, stream>>>(
      Vb, Lb, vnorm, lnorm, rowmin, colmin);
  chamfer_reduce<<<dim3(NB), dim3(256), 0, stream>>>(rowmin, colmin, out);
}

// Round 7
// 522.266 us; speedup vs baseline: 1.3385x; 1.3385x over previous
//
#include <hip/hip_runtime.h>
#include <hip/hip_bf16.h>
#include <stdint.h>

#define NB 64
#define NV 2048
#define NL 512
#define DK 512
#define BT 128
#define BK 64

typedef __attribute__((ext_vector_type(8))) short bf16x8;
typedef __attribute__((ext_vector_type(4))) float f32x4;

// order-preserving float -> uint map (for atomicMin); all-ones = +infinity sentinel
__device__ __forceinline__ unsigned enc_f(float f) {
  unsigned u = __float_as_uint(f);
  return (u & 0x80000000u) ? ~u : (u | 0x80000000u);
}
__device__ __forceinline__ float dec_f(unsigned u) {
  unsigned b = (u & 0x80000000u) ? (u ^ 0x80000000u) : ~u;
  return __uint_as_float(b);
}

// fp32 -> bf16 (RNE); inputs finite, no NaN path
__device__ __forceinline__ unsigned short f2bf(float f) {
  unsigned u = __float_as_uint(f);
  u += 0x7FFFu + ((u >> 16) & 1u);
  return (unsigned short)(u >> 16);
}
__device__ __forceinline__ unsigned pack_bf2(float lo, float hi) {
  return (unsigned)f2bf(lo) | ((unsigned)f2bf(hi) << 16);
}

// async global->LDS, 16 B per lane; LDS dest = wave-uniform base + lane*16
__device__ __forceinline__ void gload_lds16(const void* g, void* l) {
  __builtin_amdgcn_global_load_lds(
      (const __attribute__((address_space(1))) unsigned*)g,
      (__attribute__((address_space(3))) unsigned*)l, 16, 0, 0);
}

// ---------------- Pass 1: fp32 -> bf16 + exact fp32 row norms + min-sentinel init -------
// one wave per row of 512 floats; lane handles 8 consecutive elems -> one 16B store.
__global__ __launch_bounds__(256) void convert_norm(
    const float* __restrict__ video, const float* __restrict__ lang,
    unsigned short* __restrict__ Vb, unsigned short* __restrict__ Lb,
    float* __restrict__ vnorm, float* __restrict__ lnorm,
    unsigned* __restrict__ rowmin, unsigned* __restrict__ colmin) {
  const int t = threadIdx.x;
  const int lane = t & 63;
  const int row = blockIdx.x * 4 + (t >> 6);
  const int rows_v = NB * NV;

  const float* src;
  unsigned short* dst;
  float* nrm;
  unsigned* sent;
  size_t r;
  if (row < rows_v) { src = video; dst = Vb; nrm = vnorm; sent = rowmin; r = (size_t)row; }
  else              { src = lang;  dst = Lb;  nrm = lnorm; sent = colmin; r = (size_t)(row - rows_v); }

  const float4* p = (const float4*)(src + r * DK);
  const float4 a = p[lane * 2];
  const float4 b = p[lane * 2 + 1];

  float n = a.x * a.x + a.y * a.y + a.z * a.z + a.w * a.w
          + b.x * b.x + b.y * b.y + b.z * b.z + b.w * b.w;
  #pragma unroll
  for (int m = 1; m < 64; m <<= 1) n += __shfl_xor(n, m, 64);

  uint4 pk;
  pk.x = pack_bf2(a.x, a.y); pk.y = pack_bf2(a.z, a.w);
  pk.z = pack_bf2(b.x, b.y); pk.w = pack_bf2(b.z, b.w);
  ((uint4*)(dst + r * DK))[lane] = pk;
  if (lane == 0) {
    nrm[r] = n;
    sent[r] = 0xFFFFFFFFu;   // +inf sentinel for atomicMin
  }
}

// ---------------- Pass 2: bf16 GEMM + chamfer mins ----------------
// VERIFIED OPTIMUM of this session (gemm ~118 us, total ~524 us). Do not:
//  - make blocks persistent (r5: FETCH 286 MB, 197 us — kills L2/L3 sweep locality)
//  - raise launch_bounds min-waves past 4 (r6: VGPR 64->48, acc spills, 300 us)
//  - replace with 1-block/CU 256^2 phase pipelines (r1/r2: 141-162 us — counted
//    vmcnt drains starve at 8 K-iters with no co-resident blocks to hide them)
// XCD-swizzled grid: xcd = bid&7 owns 8 contiguous batches -> A/B tile re-reads hit
// that XCD's L2 instead of crossing to L3.
// block 256 = 4 waves, each 64x64 out. LDS [128][64] bf16 unpadded with XOR chunk
// swizzle (slot = chunk ^ (row&7)) -> conflict-free ds_read_b128 (measured 0).
__global__ __launch_bounds__(256, 4) void chamfer_gemm(
    const unsigned short* __restrict__ Vb, const unsigned short* __restrict__ Lb,
    const float* __restrict__ vnorm, const float* __restrict__ lnorm,
    unsigned* __restrict__ rowmin, unsigned* __restrict__ colmin) {
  __shared__ unsigned short Asm[BT][BK];
  __shared__ unsigned short Bsm[BT][BK];

  const int bid0 = blockIdx.x;
  const int bid = (bid0 & 7) * 512 + (bid0 >> 3);   // XCD-contiguous logical id
  const int b  = bid >> 6;
  const int vt = (bid >> 2) & 15;
  const int lt = bid & 3;

  const unsigned short* Ag = Vb + ((size_t)b * NV + (size_t)vt * BT) * DK;
  const unsigned short* Bg = Lb + ((size_t)b * NL + (size_t)lt * BT) * DK;

  const int t = threadIdx.x;
  const int lane = t & 63;
  const int w = t >> 6;
  const int wrow = (w >> 1) * 64;
  const int wcol = (w & 1) * 64;

  // staging: each wave stages 32 rows of A and 32 rows of B (4 instrs each, 8 rows/instr)
  const int lr = lane >> 3;        // row within 8-row group
  const int lp = lane & 7;         // dest slot within row
  const int schunk = lp ^ lr;      // source chunk (XOR swizzle)

  f32x4 acc[4][4];
  #pragma unroll
  for (int i = 0; i < 4; i++)
    #pragma unroll
    for (int j = 0; j < 4; j++)
      acc[i][j] = (f32x4){0.f, 0.f, 0.f, 0.f};

  const int c16 = lane & 15;
  const int hi  = lane >> 4;       // 0..3
  const int sw  = c16 & 7;         // read-side swizzle key (row&7)

  for (int k0 = 0; k0 < DK; k0 += BK) {
    __syncthreads();               // all waves done reading previous tile
    #pragma unroll
    for (int s = 0; s < 4; s++) {
      const int row = w * 32 + s * 8 + lr;
      gload_lds16(Ag + (size_t)row * DK + k0 + schunk * 8, &Asm[w * 32 + s * 8][0]);
      gload_lds16(Bg + (size_t)row * DK + k0 + schunk * 8, &Bsm[w * 32 + s * 8][0]);
    }
    __syncthreads();               // vmcnt(0) drain -> tile visible
    #pragma unroll
    for (int ks = 0; ks < 2; ks++) {
      const int ck = ks * 4 + hi;  // logical 16B chunk index in row
      bf16x8 af[4], bfr[4];
      #pragma unroll
      for (int i = 0; i < 4; i++)
        af[i] = *(const bf16x8*)&Asm[wrow + i * 16 + c16][(ck ^ sw) * 8];
      #pragma unroll
      for (int j = 0; j < 4; j++)
        bfr[j] = *(const bf16x8*)&Bsm[wcol + j * 16 + c16][(ck ^ sw) * 8];
      #pragma unroll
      for (int i = 0; i < 4; i++)
        #pragma unroll
        for (int j = 0; j < 4; j++)
          acc[i][j] = __builtin_amdgcn_mfma_f32_16x16x32_bf16(af[i], bfr[j], acc[i][j], 0, 0, 0);
    }
  }

  // epilogue: P = rn + cn - 2*dot; C layout col=lane&15, row=(lane>>4)*4+reg
  const int g = hi;
  const int c = c16;
  const size_t rowbase = (size_t)b * NV + (size_t)vt * BT + wrow;
  const size_t colbase = (size_t)b * NL + (size_t)lt * BT + wcol;

  float cn[4];
  #pragma unroll
  for (int j = 0; j < 4; j++) cn[j] = lnorm[colbase + j * 16 + c];

  float cmin[4];
  #pragma unroll
  for (int j = 0; j < 4; j++) cmin[j] = 3.0e38f;

  #pragma unroll
  for (int i = 0; i < 4; i++) {
    #pragma unroll
    for (int r = 0; r < 4; r++) {
      const float rn = vnorm[rowbase + i * 16 + g * 4 + r];
      float m = 3.0e38f;
      #pragma unroll
      for (int j = 0; j < 4; j++) {
        const float P = rn + cn[j] - 2.0f * acc[i][j][r];
        m = fminf(m, P);
        cmin[j] = fminf(cmin[j], P);
      }
      #pragma unroll
      for (int mm = 1; mm < 16; mm <<= 1)
        m = fminf(m, __shfl_xor(m, mm, 64));
      if (c == 0)
        atomicMin(&rowmin[rowbase + i * 16 + g * 4 + r], enc_f(m));
    }
  }
  #pragma unroll
  for (int j = 0; j < 4; j++) {
    float m = cmin[j];
    m = fminf(m, __shfl_xor(m, 16, 64));
    m = fminf(m, __shfl_xor(m, 32, 64));
    if (g == 0)
      atomicMin(&colmin[colbase + j * 16 + c], enc_f(m));
  }
}

__global__ void chamfer_reduce(const unsigned* __restrict__ rowmin,
                               const unsigned* __restrict__ colmin,
                               float* __restrict__ out) {
  const int b = blockIdx.x;
  const int t = threadIdx.x;
  float s = 0.f;
  for (int i = t; i < NV; i += 256) s += dec_f(rowmin[(size_t)b * NV + i]) * (1.0f / NV);
  for (int i = t; i < NL; i += 256) s += dec_f(colmin[(size_t)b * NL + i]) * (1.0f / NL);
  #pragma unroll
  for (int m = 1; m < 64; m <<= 1) s += __shfl_xor(s, m, 64);
  __shared__ float ws[4];
  if ((t & 63) == 0) ws[t >> 6] = s;
  __syncthreads();
  if (t == 0) out[b] = ws[0] + ws[1] + ws[2] + ws[3];
}

extern "C" void kernel_launch(void* const* d_in, const int* in_sizes, int n_in,
                              void* d_out, int out_size, void* d_ws, size_t ws_size,
                              hipStream_t stream) {
  const float* video = (const float*)d_in[0];
  const float* lang  = (const float*)d_in[1];
  float* out = (float*)d_out;

  const size_t vb_elems = (size_t)NB * NV * DK;   // 67.1M bf16
  const size_t lb_elems = (size_t)NB * NL * DK;   // 16.8M bf16

  unsigned short* Vb = (unsigned short*)d_ws;
  unsigned short* Lb = Vb + vb_elems;
  float* vnorm = (float*)(Lb + lb_elems);
  float* lnorm = vnorm + (size_t)NB * NV;
  unsigned* rowmin = (unsigned*)(lnorm + (size_t)NB * NL);
  unsigned* colmin = rowmin + (size_t)NB * NV;

  convert_norm<<<dim3((NB * NV + NB * NL) / 4), dim3(256), 0, stream>>>(
      video, lang, Vb, Lb, vnorm, lnorm, rowmin, colmin);
  chamfer_gemm<<<dim3(NB * 16 * 4), dim3(256), 0, stream>>>(
      Vb, Lb, vnorm, lnorm, rowmin, colmin);
  chamfer_reduce<<<dim3(NB), dim3(256), 0, stream>>>(rowmin, colmin, out);
}